// Round 1
// baseline (73.299 us; speedup 1.0000x reference)
//
#include <hip/hip_runtime.h>
#include <math.h>

#define NUM_EXPERTS 64
#define TOP_K 6
#define HIDDEN 2048
#define INTER 1024

// ---------------- Kernel 1: gate logits (one block per expert) ----------------
__global__ __launch_bounds__(256) void k_gate(const float* __restrict__ gw,
                                              const float* __restrict__ x,
                                              float* __restrict__ logits) {
    int e = blockIdx.x;
    int t = threadIdx.x;                       // 256 threads
    const float4* r4 = (const float4*)(gw + (size_t)e * HIDDEN);
    const float4* x4 = (const float4*)x;
    float sum = 0.f;
    // 2048/4 = 512 float4s, 256 threads -> 2 each
    #pragma unroll
    for (int i = t; i < HIDDEN / 4; i += 256) {
        float4 a = r4[i], b = x4[i];
        sum += a.x * b.x + a.y * b.y + a.z * b.z + a.w * b.w;
    }
    #pragma unroll
    for (int o = 32; o; o >>= 1) sum += __shfl_down(sum, o, 64);
    __shared__ float ls[4];
    if ((t & 63) == 0) ls[t >> 6] = sum;
    __syncthreads();
    if (t == 0) logits[e] = ls[0] + ls[1] + ls[2] + ls[3];
}

// ---------------- Kernel 2: sigmoid + bias + top-6 + weight norm ----------------
__global__ __launch_bounds__(64) void k_topk(const float* __restrict__ logits,
                                             const float* __restrict__ bias,
                                             int* __restrict__ idx,
                                             float* __restrict__ wgt) {
    int t = threadIdx.x;                       // 64 threads
    __shared__ float s_score[NUM_EXPERTS];
    __shared__ float s_biased[NUM_EXPERTS];
    float lg = logits[t];
    float sc = 1.0f / (1.0f + expf(-lg));
    s_score[t] = sc;
    s_biased[t] = sc + bias[t];
    __syncthreads();
    if (t == 0) {
        bool taken[NUM_EXPERTS];
        #pragma unroll
        for (int e = 0; e < NUM_EXPERTS; e++) taken[e] = false;
        int id[TOP_K];
        float sel[TOP_K];
        for (int k = 0; k < TOP_K; k++) {
            float best = -1e30f; int bi = 0;
            for (int e = 0; e < NUM_EXPERTS; e++) {
                // strict '>' keeps lowest index on ties, matching jax top_k
                if (!taken[e] && s_biased[e] > best) { best = s_biased[e]; bi = e; }
            }
            taken[bi] = true;
            id[k] = bi;
            sel[k] = s_score[bi];
        }
        float s = 1e-20f;
        for (int k = 0; k < TOP_K; k++) s += sel[k];
        float inv = 1.0f / s;   // SCALE = 1.0
        for (int k = 0; k < TOP_K; k++) { idx[k] = id[k]; wgt[k] = sel[k] * inv; }
    }
}

// ---------------- Kernel 3: h[k][i] = silu(w1[e_k][i].x) * (w3[e_k][i].x) ----------------
// one wave per inter-row; grid = TOP_K*INTER/4 blocks of 256 (4 waves)
__global__ __launch_bounds__(256) void k_mlp1(const float* __restrict__ w1,
                                              const float* __restrict__ w3,
                                              const float* __restrict__ x,
                                              const int* __restrict__ idx,
                                              float* __restrict__ hbuf) {
    int wave = threadIdx.x >> 6;
    int lane = threadIdx.x & 63;
    int g = blockIdx.x * 4 + wave;             // [0, TOP_K*INTER)
    int k = g >> 10;                            // / INTER
    int i = g & (INTER - 1);
    int e = idx[k];
    const float4* x4 = (const float4*)x;
    float4 xr[8];
    #pragma unroll
    for (int j = 0; j < 8; j++) xr[j] = x4[lane + 64 * j];   // x fragment in regs
    const float4* a4 = (const float4*)(w1 + ((size_t)e * INTER + i) * HIDDEN);
    const float4* b4 = (const float4*)(w3 + ((size_t)e * INTER + i) * HIDDEN);
    float sg = 0.f, su = 0.f;
    #pragma unroll
    for (int j = 0; j < 8; j++) {
        float4 a = a4[lane + 64 * j];
        sg += a.x * xr[j].x + a.y * xr[j].y + a.z * xr[j].z + a.w * xr[j].w;
        float4 b = b4[lane + 64 * j];
        su += b.x * xr[j].x + b.y * xr[j].y + b.z * xr[j].z + b.w * xr[j].w;
    }
    #pragma unroll
    for (int o = 32; o; o >>= 1) {
        sg += __shfl_down(sg, o, 64);
        su += __shfl_down(su, o, 64);
    }
    if (lane == 0) {
        float gate = sg / (1.0f + expf(-sg));   // silu
        hbuf[k * INTER + i] = gate * su;
    }
}

// ---------------- Kernel 4: out[h] = sum_k w[k] * dot(w2[e_k][h], h_k) ----------------
// one wave per output element; grid = HIDDEN/4 blocks of 256 (4 waves)
__global__ __launch_bounds__(256) void k_mlp2(const float* __restrict__ w2,
                                              const int* __restrict__ idx,
                                              const float* __restrict__ wgt,
                                              const float* __restrict__ hbuf,
                                              float* __restrict__ out) {
    int wave = threadIdx.x >> 6;
    int lane = threadIdx.x & 63;
    int h = blockIdx.x * 4 + wave;             // [0, HIDDEN)
    float acc = 0.f;
    #pragma unroll
    for (int k = 0; k < TOP_K; k++) {
        int e = idx[k];
        const float4* r4 = (const float4*)(w2 + ((size_t)e * HIDDEN + h) * INTER);
        const float4* h4 = (const float4*)(hbuf + k * INTER);
        float s = 0.f;
        #pragma unroll
        for (int j = 0; j < 4; j++) {
            float4 a = r4[lane + 64 * j];
            float4 b = h4[lane + 64 * j];
            s += a.x * b.x + a.y * b.y + a.z * b.z + a.w * b.w;
        }
        acc += wgt[k] * s;
    }
    #pragma unroll
    for (int o = 32; o; o >>= 1) acc += __shfl_down(acc, o, 64);
    if (lane == 0) out[h] = acc;
}

extern "C" void kernel_launch(void* const* d_in, const int* in_sizes, int n_in,
                              void* d_out, int out_size, void* d_ws, size_t ws_size,
                              hipStream_t stream) {
    const float* x    = (const float*)d_in[0];
    const float* gw   = (const float*)d_in[1];
    const float* bias = (const float*)d_in[2];
    const float* w1   = (const float*)d_in[3];
    const float* w2   = (const float*)d_in[4];
    const float* w3   = (const float*)d_in[5];
    float* out = (float*)d_out;

    float* ws_f   = (float*)d_ws;
    float* logits = ws_f;                       // 64 floats
    int*   idx    = (int*)(ws_f + 64);          // 6 ints
    float* wgt    = ws_f + 72;                  // 6 floats
    float* hbuf   = ws_f + 128;                 // TOP_K*INTER = 6144 floats

    k_gate<<<NUM_EXPERTS, 256, 0, stream>>>(gw, x, logits);
    k_topk<<<1, 64, 0, stream>>>(logits, bias, idx, wgt);
    k_mlp1<<<TOP_K * INTER / 4, 256, 0, stream>>>(w1, w3, x, idx, hbuf);
    k_mlp2<<<HIDDEN / 4, 256, 0, stream>>>(w2, idx, wgt, hbuf, out);
}

// Round 2
// 40.474 us; speedup vs baseline: 1.8110x; 1.8110x over previous
//
#include <hip/hip_runtime.h>
#include <math.h>

#define NUM_EXPERTS 64
#define TOP_K 6
#define HIDDEN 2048
#define INTER 1024

// ---------------- Kernel 1: gate logits (one block per expert) ----------------
__global__ __launch_bounds__(256) void k_gate(const float* __restrict__ gw,
                                              const float* __restrict__ x,
                                              float* __restrict__ logits) {
    int e = blockIdx.x;
    int t = threadIdx.x;                       // 256 threads
    const float4* r4 = (const float4*)(gw + (size_t)e * HIDDEN);
    const float4* x4 = (const float4*)x;
    float sum = 0.f;
    #pragma unroll
    for (int i = t; i < HIDDEN / 4; i += 256) {
        float4 a = r4[i], b = x4[i];
        sum += a.x * b.x + a.y * b.y + a.z * b.z + a.w * b.w;
    }
    #pragma unroll
    for (int o = 32; o; o >>= 1) sum += __shfl_down(sum, o, 64);
    __shared__ float ls[4];
    if ((t & 63) == 0) ls[t >> 6] = sum;
    __syncthreads();
    if (t == 0) logits[e] = ls[0] + ls[1] + ls[2] + ls[3];
}

// ---------------- Kernel 2: sigmoid + bias + top-6, fully wave-parallel ----------------
// 64 threads, one expert per lane. 6 rounds of 64-lane argmax in registers.
__global__ __launch_bounds__(64) void k_topk(const float* __restrict__ logits,
                                             const float* __restrict__ bias,
                                             int* __restrict__ idx,
                                             float* __restrict__ wgt) {
    int t = threadIdx.x;                       // 64 threads = 64 experts
    float lg = logits[t];
    float sc = 1.0f / (1.0f + expf(-lg));      // unbiased score (gate weight)
    float cur = sc + bias[t];                  // biased score (routing key)

    int i0, i1, i2, i3, i4, i5;
    float s0, s1, s2, s3, s4, s5;

#define ARGMAX_ROUND(IK, SK)                                                   \
    {                                                                          \
        float v = cur; int li = t;                                             \
        _Pragma("unroll")                                                      \
        for (int o = 32; o; o >>= 1) {                                         \
            float ov = __shfl_down(v, o, 64);                                  \
            int   oi = __shfl_down(li, o, 64);                                 \
            if (ov > v || (ov == v && oi < li)) { v = ov; li = oi; }           \
        }                                                                      \
        li = __shfl(li, 0, 64);                                                \
        IK = li;                                                               \
        SK = __shfl(sc, li, 64);                                               \
        if (t == li) cur = -1e30f;                                             \
    }

    ARGMAX_ROUND(i0, s0)
    ARGMAX_ROUND(i1, s1)
    ARGMAX_ROUND(i2, s2)
    ARGMAX_ROUND(i3, s3)
    ARGMAX_ROUND(i4, s4)
    ARGMAX_ROUND(i5, s5)
#undef ARGMAX_ROUND

    float inv = 1.0f / (s0 + s1 + s2 + s3 + s4 + s5 + 1e-20f);  // SCALE = 1.0
    if (t == 0) {
        idx[0] = i0; idx[1] = i1; idx[2] = i2; idx[3] = i3; idx[4] = i4; idx[5] = i5;
        wgt[0] = s0 * inv; wgt[1] = s1 * inv; wgt[2] = s2 * inv;
        wgt[3] = s3 * inv; wgt[4] = s4 * inv; wgt[5] = s5 * inv;
    }
}

// ---------------- Kernel 3: h[k][i] = silu(w1[e_k][i].x) * (w3[e_k][i].x) ----------------
// one wave per inter-row; grid = TOP_K*INTER/4 blocks of 256 (4 waves). x staged in LDS.
__global__ __launch_bounds__(256) void k_mlp1(const float* __restrict__ w1,
                                              const float* __restrict__ w3,
                                              const float* __restrict__ x,
                                              const int* __restrict__ idx,
                                              float* __restrict__ hbuf) {
    __shared__ float4 xs[HIDDEN / 4];          // 8 KB
    int t = threadIdx.x;
    const float4* x4 = (const float4*)x;
    #pragma unroll
    for (int i = t; i < HIDDEN / 4; i += 256) xs[i] = x4[i];
    __syncthreads();

    int wave = t >> 6;
    int lane = t & 63;
    int g = blockIdx.x * 4 + wave;             // [0, TOP_K*INTER)
    int k = g >> 10;                           // / INTER
    int i = g & (INTER - 1);
    int e = idx[k];

    float4 xr[8];
    #pragma unroll
    for (int j = 0; j < 8; j++) xr[j] = xs[lane + 64 * j];

    const float4* a4 = (const float4*)(w1 + ((size_t)e * INTER + i) * HIDDEN);
    const float4* b4 = (const float4*)(w3 + ((size_t)e * INTER + i) * HIDDEN);
    float sg = 0.f, su = 0.f;
    #pragma unroll
    for (int j = 0; j < 8; j++) {
        float4 a = a4[lane + 64 * j];
        sg += a.x * xr[j].x + a.y * xr[j].y + a.z * xr[j].z + a.w * xr[j].w;
        float4 b = b4[lane + 64 * j];
        su += b.x * xr[j].x + b.y * xr[j].y + b.z * xr[j].z + b.w * xr[j].w;
    }
    #pragma unroll
    for (int o = 32; o; o >>= 1) {
        sg += __shfl_down(sg, o, 64);
        su += __shfl_down(su, o, 64);
    }
    if (lane == 0) {
        float gate = sg / (1.0f + expf(-sg));   // silu
        hbuf[k * INTER + i] = gate * su;
    }
}

// ---------------- Kernel 4: out[h] = sum_k w[k] * dot(w2[e_k][h], h_k) ----------------
// one wave per output element; grid = HIDDEN/4 blocks of 256 (4 waves).
// hbuf (24 KB) + idx/wgt staged in LDS per block.
__global__ __launch_bounds__(256) void k_mlp2(const float* __restrict__ w2,
                                              const int* __restrict__ idx,
                                              const float* __restrict__ wgt,
                                              const float* __restrict__ hbuf,
                                              float* __restrict__ out) {
    __shared__ float4 hs[TOP_K * INTER / 4];   // 24 KB
    __shared__ int   sidx[TOP_K];
    __shared__ float swgt[TOP_K];
    int t = threadIdx.x;
    if (t < TOP_K) { sidx[t] = idx[t]; swgt[t] = wgt[t]; }
    const float4* h4 = (const float4*)hbuf;
    #pragma unroll
    for (int i = t; i < TOP_K * INTER / 4; i += 256) hs[i] = h4[i];
    __syncthreads();

    int wave = t >> 6;
    int lane = t & 63;
    int h = blockIdx.x * 4 + wave;             // [0, HIDDEN)
    float acc = 0.f;
    #pragma unroll
    for (int k = 0; k < TOP_K; k++) {
        int e = sidx[k];
        const float4* r4 = (const float4*)(w2 + ((size_t)e * HIDDEN + h) * INTER);
        float s = 0.f;
        #pragma unroll
        for (int j = 0; j < 4; j++) {
            float4 a = r4[lane + 64 * j];
            float4 b = hs[k * (INTER / 4) + lane + 64 * j];
            s += a.x * b.x + a.y * b.y + a.z * b.z + a.w * b.w;
        }
        acc += swgt[k] * s;
    }
    #pragma unroll
    for (int o = 32; o; o >>= 1) acc += __shfl_down(acc, o, 64);
    if (lane == 0) out[h] = acc;
}

extern "C" void kernel_launch(void* const* d_in, const int* in_sizes, int n_in,
                              void* d_out, int out_size, void* d_ws, size_t ws_size,
                              hipStream_t stream) {
    const float* x    = (const float*)d_in[0];
    const float* gw   = (const float*)d_in[1];
    const float* bias = (const float*)d_in[2];
    const float* w1   = (const float*)d_in[3];
    const float* w2   = (const float*)d_in[4];
    const float* w3   = (const float*)d_in[5];
    float* out = (float*)d_out;

    float* ws_f   = (float*)d_ws;
    float* logits = ws_f;                       // 64 floats
    int*   idx    = (int*)(ws_f + 64);          // 6 ints
    float* wgt    = ws_f + 72;                  // 6 floats
    float* hbuf   = ws_f + 128;                 // TOP_K*INTER = 6144 floats

    k_gate<<<NUM_EXPERTS, 256, 0, stream>>>(gw, x, logits);
    k_topk<<<1, 64, 0, stream>>>(logits, bias, idx, wgt);
    k_mlp1<<<TOP_K * INTER / 4, 256, 0, stream>>>(w1, w3, x, idx, hbuf);
    k_mlp2<<<HIDDEN / 4, 256, 0, stream>>>(w2, idx, wgt, hbuf, out);
}